// Round 7
// baseline (909.469 us; speedup 1.0000x reference)
//
#include <hip/hip_runtime.h>
#include <math.h>

#define NB 16
#define NF 768
#define NN 1024
#define KSEL 30

// ---------------- K1: per-(b,f) mean and 1/(std+1e-6) over the 1024 contiguous samples
__global__ __launch_bounds__(256) void k_stats(const float* __restrict__ data,
                                               double* __restrict__ meanv,
                                               double* __restrict__ invv) {
    int bf = blockIdx.x;
    int tid = threadIdx.x;
    const float4* p = reinterpret_cast<const float4*>(data + (size_t)bf * NN);
    float4 v = p[tid];
    double s  = (double)v.x + (double)v.y + (double)v.z + (double)v.w;
    double s2 = (double)v.x * (double)v.x + (double)v.y * (double)v.y +
                (double)v.z * (double)v.z + (double)v.w * (double)v.w;
    __shared__ double r1[256], r2[256];
    r1[tid] = s; r2[tid] = s2;
    __syncthreads();
    for (int st = 128; st > 0; st >>= 1) {
        if (tid < st) { r1[tid] += r1[tid + st]; r2[tid] += r2[tid + st]; }
        __syncthreads();
    }
    if (tid == 0) {
        double S = r1[0], S2 = r2[0];
        double mean = S / (double)NN;
        double var = (S2 - S * mean) / (double)(NN - 1);
        if (var < 0.0) var = 0.0;
        meanv[bf] = mean;
        invv[bf]  = 1.0 / (sqrt(var) + 1e-6);
    }
}

// ---------------- K2a: partial sq over f-chunks of 96 (512 blocks for parallelism)
__global__ __launch_bounds__(256) void k_sq1(const float* __restrict__ data,
                                             const double* __restrict__ meanv,
                                             const double* __restrict__ invv,
                                             double* __restrict__ psum) {
    int b = blockIdx.x >> 2;
    int n = ((blockIdx.x & 3) << 8) + threadIdx.x;
    int y = blockIdx.y;                 // f-chunk 0..7
    const float* base = data + (size_t)b * NF * NN;
    const double* mb = meanv + (size_t)b * NF;
    const double* ib = invv + (size_t)b * NF;
    double acc = 0.0;
    int f0 = y * 96;
    for (int f = f0; f < f0 + 96; ++f) {
        float x = base[(size_t)f * NN + n];
        float xn = (float)(((double)x - mb[f]) * ib[f]);
        acc = fma((double)xn, (double)xn, acc);
    }
    psum[((size_t)(b * 8 + y)) * NN + n] = acc;
}

// ---------------- K2b: reduce 8 partials -> sq[b,n]
__global__ __launch_bounds__(256) void k_sq2(const double* __restrict__ psum,
                                             double* __restrict__ sq) {
    int g = blockIdx.x * 256 + threadIdx.x;   // 0..16383
    int b = g >> 10, n = g & (NN - 1);
    double acc = 0.0;
    #pragma unroll
    for (int y = 0; y < 8; ++y) acc += psum[((size_t)(b * 8 + y)) * NN + n];
    sq[g] = acc;
}

// ---------------- K0: deg[n] = row-sum of adj (coalesced, one block per row)
// deg values are small integer counts -> exact in any summation order.
__global__ __launch_bounds__(256) void k_deg(const float* __restrict__ adj, float* __restrict__ deg) {
    int n = blockIdx.x;
    int tid = threadIdx.x;
    const float4* row = reinterpret_cast<const float4*>(adj + (size_t)n * NN);
    float4 v = row[tid];
    float s = v.x + v.y + v.z + v.w;
    __shared__ float red[256];
    red[tid] = s; __syncthreads();
    for (int st = 128; st > 0; st >>= 1) {
        if (tid < st) red[tid] += red[tid + st];
        __syncthreads();
    }
    if (tid == 0) deg[n] = red[0];
}

// ---------------- K3: symmetric batched Gram + d2 epilogue (f64 accum)
// Round-2 proven-correct structure: 128x128 tiles, triangular pairs (36 of 64),
// 8x8 f64 acc per thread. __launch_bounds__(256,1) lifts the VGPR cap that
// caused round-2's accumulator spill (VGPR_Count=104 -> scratch traffic).
__global__ __launch_bounds__(256, 1) void k_gemm_sym(const float* __restrict__ data,
                                                     const double* __restrict__ meanv,
                                                     const double* __restrict__ invv,
                                                     const double* __restrict__ sq,
                                                     double* __restrict__ d2buf, int b0) {
    __shared__ float As[32][128];
    __shared__ float Bs[32][128];
    int tid = threadIdx.x;
    // decode upper-triangular tile pair (ti, tj), ti <= tj, 8x8 tiles of 128
    int t = blockIdx.x;
    int ti = 0, rem = t;
    while (rem >= 8 - ti) { rem -= 8 - ti; ++ti; }
    int tj = ti + rem;
    int n0 = ti * 128, m0 = tj * 128;
    int bb = blockIdx.z;
    int b = b0 + bb;
    const float* base = data + (size_t)b * NF * NN;
    const double* mb = meanv + (size_t)b * NF;
    const double* ib = invv + (size_t)b * NF;
    int tx = tid & 15, ty = tid >> 4;

    double acc[8][8];
    #pragma unroll
    for (int i = 0; i < 8; ++i)
        #pragma unroll
        for (int j = 0; j < 8; ++j) acc[i][j] = 0.0;

    for (int f0 = 0; f0 < NF; f0 += 32) {
        #pragma unroll
        for (int r = 0; r < 4; ++r) {
            int idx = r * 256 + tid;   // 0..1023
            int k = idx >> 5, c4 = idx & 31;
            double mk = mb[f0 + k], ik = ib[f0 + k];
            float4 a = reinterpret_cast<const float4*>(base + (size_t)(f0 + k) * NN + n0)[c4];
            float4 c = reinterpret_cast<const float4*>(base + (size_t)(f0 + k) * NN + m0)[c4];
            float4 an, cn;
            an.x = (float)(((double)a.x - mk) * ik);
            an.y = (float)(((double)a.y - mk) * ik);
            an.z = (float)(((double)a.z - mk) * ik);
            an.w = (float)(((double)a.w - mk) * ik);
            cn.x = (float)(((double)c.x - mk) * ik);
            cn.y = (float)(((double)c.y - mk) * ik);
            cn.z = (float)(((double)c.z - mk) * ik);
            cn.w = (float)(((double)c.w - mk) * ik);
            reinterpret_cast<float4*>(&As[k][0])[c4] = an;
            reinterpret_cast<float4*>(&Bs[k][0])[c4] = cn;
        }
        __syncthreads();
        #pragma unroll 4
        for (int k = 0; k < 32; ++k) {
            float4 a0 = *reinterpret_cast<const float4*>(&As[k][tx * 4]);
            float4 a1 = *reinterpret_cast<const float4*>(&As[k][tx * 4 + 64]);
            float4 c0 = *reinterpret_cast<const float4*>(&Bs[k][ty * 4]);
            float4 c1 = *reinterpret_cast<const float4*>(&Bs[k][ty * 4 + 64]);
            double av[8] = {(double)a0.x, (double)a0.y, (double)a0.z, (double)a0.w,
                            (double)a1.x, (double)a1.y, (double)a1.z, (double)a1.w};
            double bv[8] = {(double)c0.x, (double)c0.y, (double)c0.z, (double)c0.w,
                            (double)c1.x, (double)c1.y, (double)c1.z, (double)c1.w};
            #pragma unroll
            for (int i = 0; i < 8; ++i)
                #pragma unroll
                for (int j = 0; j < 8; ++j)
                    acc[i][j] = fma(av[i], bv[j], acc[i][j]);
        }
        __syncthreads();
    }

    const double* sqb = sq + (size_t)b * NN;
    bool mirror = (ti != tj);
    #pragma unroll
    for (int i = 0; i < 8; ++i) {
        int n = n0 + ((i & 4) << 4) + tx * 4 + (i & 3);
        double sn = sqb[n];
        #pragma unroll
        for (int j = 0; j < 8; ++j) {
            int m = m0 + ((j & 4) << 4) + ty * 4 + (j & 3);
            double d2 = sn + sqb[m] - 2.0 * acc[i][j];
            if (d2 < 0.0) d2 = 0.0;
            d2buf[((size_t)bb * NN + n) * NN + m] = d2;
            if (mirror) d2buf[((size_t)bb * NN + m) * NN + n] = d2;
        }
    }
}

// ---------------- K4: per-row 31st smallest (index KSEL of ascending sort, diag included)
__global__ __launch_bounds__(256) void k_select(const double* __restrict__ d2buf,
                                                double* __restrict__ sel, int b0) {
    int rowc = blockIdx.x * 4 + (threadIdx.x >> 6);  // row within chunk
    int lane = threadIdx.x & 63;
    const double* r = d2buf + (size_t)rowc * NN;
    double v[16];
    #pragma unroll
    for (int s = 0; s < 16; ++s) v[s] = r[s * 64 + lane];
    double kth = 0.0;
    for (int t = 0; t <= KSEL; ++t) {
        double mv = v[0]; int ms = 0;
        #pragma unroll
        for (int s = 1; s < 16; ++s) { if (v[s] < mv) { mv = v[s]; ms = s; } }
        int mid = ms * 64 + lane;
        #pragma unroll
        for (int off = 1; off < 64; off <<= 1) {
            double ov = __shfl_xor(mv, off);
            int oid  = __shfl_xor(mid, off);
            if (ov < mv || (ov == mv && oid < mid)) { mv = ov; mid = oid; }
        }
        kth = mv;
        if (t < KSEL) {
            #pragma unroll
            for (int s = 0; s < 16; ++s) {
                if (s * 64 + lane == mid) v[s] = 1e300;
            }
        }
    }
    if (lane == 0) sel[(size_t)b0 * NN + rowc] = sqrt(kth);
}

// ---------------- K5: R2[b] = (mean_n sel)^2
__global__ __launch_bounds__(256) void k_R(const double* __restrict__ sel,
                                           double* __restrict__ R2v, int b0) {
    int b = b0 + blockIdx.x;
    int tid = threadIdx.x;
    const double* s = sel + (size_t)b * NN;
    double acc = s[tid] + s[tid + 256] + s[tid + 512] + s[tid + 768];
    __shared__ double red[256];
    red[tid] = acc; __syncthreads();
    for (int st = 128; st > 0; st >>= 1) {
        if (tid < st) red[tid] += red[tid + st];
        __syncthreads();
    }
    if (tid == 0) { double R = red[0] / (double)NN; R2v[b] = R * R; }
}

// ---------------- K6: per-row counts (samples: d2<R2, neighbors: adj&&d2>0&&d2<R2)
__global__ __launch_bounds__(256) void k_counts(const double* __restrict__ d2buf,
                                                const float* __restrict__ adj,
                                                const double* __restrict__ R2v,
                                                int* __restrict__ samplesN,
                                                int* __restrict__ neighborN,
                                                int* __restrict__ ssum, int b0) {
    int rowc = blockIdx.x;
    int g = b0 * NN + rowc;
    int b = g >> 10;
    int n = g & (NN - 1);
    double R2 = R2v[b];
    const double* r = d2buf + (size_t)rowc * NN;
    const float* arow = adj + (size_t)n * NN;
    int tid = threadIdx.x;
    int cs = 0, cn = 0;
    for (int i = tid; i < NN; i += 256) {
        double d = r[i];
        int lt = (d < R2) ? 1 : 0;
        cs += lt;
        float a = arow[i];
        if (a != 0.0f && d > 0.0 && lt) cn++;
    }
    __shared__ int rs[256], rn[256];
    rs[tid] = cs; rn[tid] = cn; __syncthreads();
    for (int st = 128; st > 0; st >>= 1) {
        if (tid < st) { rs[tid] += rs[tid + st]; rn[tid] += rn[tid + st]; }
        __syncthreads();
    }
    if (tid == 0) {
        samplesN[g]  = rs[0];
        neighborN[g] = rn[0];
        atomicAdd(&ssum[b], rs[0]);
    }
}

// ---------------- K7: fp32 scores, exact reference op order
__global__ __launch_bounds__(256) void k_score(const int* __restrict__ samplesN,
                                               const int* __restrict__ neighborN,
                                               const int* __restrict__ ssum,
                                               const float* __restrict__ deg,
                                               float* __restrict__ scoreb,
                                               float* __restrict__ outScore) {
    int g = blockIdx.x * 256 + threadIdx.x;
    int b = g >> 10, n = g & (NN - 1);
    float s  = (float)samplesN[g];
    float nb = (float)neighborN[g];
    float means = (float)ssum[b] / 1024.0f;
    float spatial  = nb / deg[n];
    float temporal = s / (s + means);
    float sc = (2.0f - spatial) - temporal;
    scoreb[g] = sc;
    outScore[g] = sc;
}

// ---------------- K8: stable double-argsort rank + keep mask
__global__ __launch_bounds__(1024) void k_rank(const float* __restrict__ scoreb,
                                               const float* __restrict__ pptr,
                                               float* __restrict__ keepf) {
    int b = blockIdx.x;
    int i = threadIdx.x;
    __shared__ float s[NN];
    s[i] = scoreb[b * NN + i];
    __syncthreads();
    float si = s[i];
    int rank = 0;
    for (int j = 0; j < NN; ++j) {
        float sj = s[j];
        if (sj < si || (sj == si && j < i)) rank++;
    }
    float cut = (float)NN * pptr[0];
    keepf[b * NN + i] = ((float)rank < cut) ? 1.0f : 0.0f;
}

// ---------------- K9: out = data * keep (broadcast over C,H)
__global__ __launch_bounds__(256) void k_apply(const float* __restrict__ data,
                                               const float* __restrict__ keepf,
                                               float* __restrict__ out) {
    size_t g4 = (size_t)blockIdx.x * 256 + threadIdx.x;
    size_t flat = g4 << 2;
    int w = (int)(flat & (NN - 1));
    int b = (int)(flat / ((size_t)NF * NN));
    float4 v = reinterpret_cast<const float4*>(data)[g4];
    const float4* kb = reinterpret_cast<const float4*>(keepf + b * NN + w);
    float4 kv = kb[0];
    float4 o;
    o.x = v.x * kv.x; o.y = v.y * kv.y; o.z = v.z * kv.z; o.w = v.w * kv.w;
    reinterpret_cast<float4*>(out)[g4] = o;
}

extern "C" void kernel_launch(void* const* d_in, const int* in_sizes, int n_in,
                              void* d_out, int out_size, void* d_ws, size_t ws_size,
                              hipStream_t stream) {
    const float* data = (const float*)d_in[0];
    const float* adj  = (const float*)d_in[1];
    const float* pptr = (const float*)d_in[4];
    float* out = (float*)d_out;
    float* outScore = out + (size_t)NB * NF * NN;

    char* w = (char*)d_ws;
    size_t off = 0;
    auto alloc = [&](size_t bytes) -> void* {
        off = (off + 255) & ~(size_t)255;
        void* p = w + off;
        off += bytes;
        return p;
    };
    double* meanv  = (double*)alloc((size_t)NB * NF * 8);
    double* invv   = (double*)alloc((size_t)NB * NF * 8);
    double* sq     = (double*)alloc((size_t)NB * NN * 8);
    double* psum   = (double*)alloc((size_t)NB * 8 * NN * 8);
    double* sel    = (double*)alloc((size_t)NB * NN * 8);
    double* R2v    = (double*)alloc((size_t)NB * 8);
    int* samplesN  = (int*)alloc((size_t)NB * NN * 4);
    int* neighborN = (int*)alloc((size_t)NB * NN * 4);
    int* ssum      = (int*)alloc((size_t)NB * 4);
    float* deg     = (float*)alloc((size_t)NN * 4);
    float* scoreb  = (float*)alloc((size_t)NB * NN * 4);
    float* keepf   = (float*)alloc((size_t)NB * NN * 4);
    off = (off + 255) & ~(size_t)255;
    size_t rem = (ws_size > off) ? (ws_size - off) : 0;
    int chunk = (int)(rem / ((size_t)NN * NN * 8));
    if (chunk > NB) chunk = NB;
    if (chunk < 1) chunk = 1;
    double* d2buf = (double*)(w + off);

    hipMemsetAsync(ssum, 0, NB * 4, stream);
    k_stats<<<NB * NF, 256, 0, stream>>>(data, meanv, invv);
    k_sq1<<<dim3(NB * 4, 8), 256, 0, stream>>>(data, meanv, invv, psum);
    k_sq2<<<NB * NN / 256, 256, 0, stream>>>(psum, sq);
    k_deg<<<NN, 256, 0, stream>>>(adj, deg);

    for (int b0 = 0; b0 < NB; b0 += chunk) {
        int c = (NB - b0 < chunk) ? (NB - b0) : chunk;
        dim3 gg(36, 1, c);
        k_gemm_sym<<<gg, 256, 0, stream>>>(data, meanv, invv, sq, d2buf, b0);
        k_select<<<c * NN / 4, 256, 0, stream>>>(d2buf, sel, b0);
        k_R<<<c, 256, 0, stream>>>(sel, R2v, b0);
        k_counts<<<c * NN, 256, 0, stream>>>(d2buf, adj, R2v, samplesN, neighborN, ssum, b0);
    }

    k_score<<<NB * NN / 256, 256, 0, stream>>>(samplesN, neighborN, ssum, deg, scoreb, outScore);
    k_rank<<<NB, 1024, 0, stream>>>(scoreb, pptr, keepf);
    k_apply<<<(NB * NF * NN) / (256 * 4), 256, 0, stream>>>(data, keepf, out);
}

// Round 8
// 898.659 us; speedup vs baseline: 1.0120x; 1.0120x over previous
//
#include <hip/hip_runtime.h>
#include <math.h>

#define NB 16
#define NF 768
#define NN 1024
#define KSEL 30

// ---------------- K1: per-(b,f) mean and 1/(std+1e-6) over the 1024 contiguous samples
__global__ __launch_bounds__(256) void k_stats(const float* __restrict__ data,
                                               double* __restrict__ meanv,
                                               double* __restrict__ invv) {
    int bf = blockIdx.x;
    int tid = threadIdx.x;
    const float4* p = reinterpret_cast<const float4*>(data + (size_t)bf * NN);
    float4 v = p[tid];
    double s  = (double)v.x + (double)v.y + (double)v.z + (double)v.w;
    double s2 = (double)v.x * (double)v.x + (double)v.y * (double)v.y +
                (double)v.z * (double)v.z + (double)v.w * (double)v.w;
    __shared__ double r1[256], r2[256];
    r1[tid] = s; r2[tid] = s2;
    __syncthreads();
    for (int st = 128; st > 0; st >>= 1) {
        if (tid < st) { r1[tid] += r1[tid + st]; r2[tid] += r2[tid + st]; }
        __syncthreads();
    }
    if (tid == 0) {
        double S = r1[0], S2 = r2[0];
        double mean = S / (double)NN;
        double var = (S2 - S * mean) / (double)(NN - 1);
        if (var < 0.0) var = 0.0;
        meanv[bf] = mean;
        invv[bf]  = 1.0 / (sqrt(var) + 1e-6);
    }
}

// ---------------- K2a: partial sq over f-chunks of 96 (512 blocks for parallelism)
__global__ __launch_bounds__(256) void k_sq1(const float* __restrict__ data,
                                             const double* __restrict__ meanv,
                                             const double* __restrict__ invv,
                                             double* __restrict__ psum) {
    int b = blockIdx.x >> 2;
    int n = ((blockIdx.x & 3) << 8) + threadIdx.x;
    int y = blockIdx.y;                 // f-chunk 0..7
    const float* base = data + (size_t)b * NF * NN;
    const double* mb = meanv + (size_t)b * NF;
    const double* ib = invv + (size_t)b * NF;
    double acc = 0.0;
    int f0 = y * 96;
    for (int f = f0; f < f0 + 96; ++f) {
        float x = base[(size_t)f * NN + n];
        float xn = (float)(((double)x - mb[f]) * ib[f]);
        acc = fma((double)xn, (double)xn, acc);
    }
    psum[((size_t)(b * 8 + y)) * NN + n] = acc;
}

// ---------------- K2b: reduce 8 partials -> sq[b,n]
__global__ __launch_bounds__(256) void k_sq2(const double* __restrict__ psum,
                                             double* __restrict__ sq) {
    int g = blockIdx.x * 256 + threadIdx.x;   // 0..16383
    int b = g >> 10, n = g & (NN - 1);
    double acc = 0.0;
    #pragma unroll
    for (int y = 0; y < 8; ++y) acc += psum[((size_t)(b * 8 + y)) * NN + n];
    sq[g] = acc;
}

// ---------------- K0: deg[n] = row-sum of adj (coalesced, one block per row)
__global__ __launch_bounds__(256) void k_deg(const float* __restrict__ adj, float* __restrict__ deg) {
    int n = blockIdx.x;
    int tid = threadIdx.x;
    const float4* row = reinterpret_cast<const float4*>(adj + (size_t)n * NN);
    float4 v = row[tid];
    float s = v.x + v.y + v.z + v.w;
    __shared__ float red[256];
    red[tid] = s; __syncthreads();
    for (int st = 128; st > 0; st >>= 1) {
        if (tid < st) red[tid] += red[tid + st];
        __syncthreads();
    }
    if (tid == 0) deg[n] = red[0];
}

// ---------------- K3: symmetric batched Gram + d2 epilogue (f64 accum)
// 128x128 tile, 512 threads, 4x8 acc/thread (64 f64 VGPR - under the ~104 cap).
// B-fragment read via LDS broadcast (<=2 distinct addrs per wave = free).
// Triangular tile pairs (36 of 64) + mirror write.
__global__ __launch_bounds__(512) void k_gemm_sym(const float* __restrict__ data,
                                                  const double* __restrict__ meanv,
                                                  const double* __restrict__ invv,
                                                  const double* __restrict__ sq,
                                                  double* __restrict__ d2buf, int b0) {
    __shared__ float As[32][128];
    __shared__ float Bs[32][128];
    int tid = threadIdx.x;
    int tx = tid & 31;          // row group: rows tx*4 .. tx*4+3
    int ty = tid >> 5;          // col group: cols ty*8 .. ty*8+7
    int t = blockIdx.x;
    int ti = 0, rem = t;
    while (rem >= 8 - ti) { rem -= 8 - ti; ++ti; }
    int tj = ti + rem;
    int n0 = ti * 128, m0 = tj * 128;
    int bb = blockIdx.z;
    int b = b0 + bb;
    const float* base = data + (size_t)b * NF * NN;
    const double* mb = meanv + (size_t)b * NF;
    const double* ib = invv + (size_t)b * NF;

    double acc[4][8];
    #pragma unroll
    for (int i = 0; i < 4; ++i)
        #pragma unroll
        for (int j = 0; j < 8; ++j) acc[i][j] = 0.0;

    for (int f0 = 0; f0 < NF; f0 += 32) {
        #pragma unroll
        for (int r = 0; r < 2; ++r) {
            int idx = r * 512 + tid;   // 0..1023 float4 slots
            int k = idx >> 5, c4 = idx & 31;
            double mk = mb[f0 + k], ik = ib[f0 + k];
            float4 a = reinterpret_cast<const float4*>(base + (size_t)(f0 + k) * NN + n0)[c4];
            float4 c = reinterpret_cast<const float4*>(base + (size_t)(f0 + k) * NN + m0)[c4];
            float4 an, cn;
            an.x = (float)(((double)a.x - mk) * ik);
            an.y = (float)(((double)a.y - mk) * ik);
            an.z = (float)(((double)a.z - mk) * ik);
            an.w = (float)(((double)a.w - mk) * ik);
            cn.x = (float)(((double)c.x - mk) * ik);
            cn.y = (float)(((double)c.y - mk) * ik);
            cn.z = (float)(((double)c.z - mk) * ik);
            cn.w = (float)(((double)c.w - mk) * ik);
            reinterpret_cast<float4*>(&As[k][0])[c4] = an;
            reinterpret_cast<float4*>(&Bs[k][0])[c4] = cn;
        }
        __syncthreads();
        #pragma unroll 4
        for (int k = 0; k < 32; ++k) {
            float4 av4 = *reinterpret_cast<const float4*>(&As[k][tx * 4]);
            float4 bv0 = *reinterpret_cast<const float4*>(&Bs[k][ty * 8]);
            float4 bv1 = *reinterpret_cast<const float4*>(&Bs[k][ty * 8 + 4]);
            double a0 = av4.x, a1 = av4.y, a2 = av4.z, a3 = av4.w;
            double b0d = bv0.x, b1d = bv0.y, b2d = bv0.z, b3d = bv0.w;
            double b4d = bv1.x, b5d = bv1.y, b6d = bv1.z, b7d = bv1.w;
            acc[0][0] = fma(a0, b0d, acc[0][0]); acc[0][1] = fma(a0, b1d, acc[0][1]);
            acc[0][2] = fma(a0, b2d, acc[0][2]); acc[0][3] = fma(a0, b3d, acc[0][3]);
            acc[0][4] = fma(a0, b4d, acc[0][4]); acc[0][5] = fma(a0, b5d, acc[0][5]);
            acc[0][6] = fma(a0, b6d, acc[0][6]); acc[0][7] = fma(a0, b7d, acc[0][7]);
            acc[1][0] = fma(a1, b0d, acc[1][0]); acc[1][1] = fma(a1, b1d, acc[1][1]);
            acc[1][2] = fma(a1, b2d, acc[1][2]); acc[1][3] = fma(a1, b3d, acc[1][3]);
            acc[1][4] = fma(a1, b4d, acc[1][4]); acc[1][5] = fma(a1, b5d, acc[1][5]);
            acc[1][6] = fma(a1, b6d, acc[1][6]); acc[1][7] = fma(a1, b7d, acc[1][7]);
            acc[2][0] = fma(a2, b0d, acc[2][0]); acc[2][1] = fma(a2, b1d, acc[2][1]);
            acc[2][2] = fma(a2, b2d, acc[2][2]); acc[2][3] = fma(a2, b3d, acc[2][3]);
            acc[2][4] = fma(a2, b4d, acc[2][4]); acc[2][5] = fma(a2, b5d, acc[2][5]);
            acc[2][6] = fma(a2, b6d, acc[2][6]); acc[2][7] = fma(a2, b7d, acc[2][7]);
            acc[3][0] = fma(a3, b0d, acc[3][0]); acc[3][1] = fma(a3, b1d, acc[3][1]);
            acc[3][2] = fma(a3, b2d, acc[3][2]); acc[3][3] = fma(a3, b3d, acc[3][3]);
            acc[3][4] = fma(a3, b4d, acc[3][4]); acc[3][5] = fma(a3, b5d, acc[3][5]);
            acc[3][6] = fma(a3, b6d, acc[3][6]); acc[3][7] = fma(a3, b7d, acc[3][7]);
        }
        __syncthreads();
    }

    const double* sqb = sq + (size_t)b * NN;
    bool mirror = (ti != tj);
    #pragma unroll
    for (int i = 0; i < 4; ++i) {
        int n = n0 + tx * 4 + i;
        double sn = sqb[n];
        #pragma unroll
        for (int j = 0; j < 8; ++j) {
            int m = m0 + ty * 8 + j;
            double d2 = sn + sqb[m] - 2.0 * acc[i][j];
            if (d2 < 0.0) d2 = 0.0;
            d2buf[((size_t)bb * NN + n) * NN + m] = d2;
            if (mirror) d2buf[((size_t)bb * NN + m) * NN + n] = d2;
        }
    }
}

// ---------------- K4: per-row 31st smallest (index KSEL of ascending sort, diag included)
__global__ __launch_bounds__(256) void k_select(const double* __restrict__ d2buf,
                                                double* __restrict__ sel, int b0) {
    int rowc = blockIdx.x * 4 + (threadIdx.x >> 6);  // row within chunk
    int lane = threadIdx.x & 63;
    const double* r = d2buf + (size_t)rowc * NN;
    double v[16];
    #pragma unroll
    for (int s = 0; s < 16; ++s) v[s] = r[s * 64 + lane];
    double kth = 0.0;
    for (int t = 0; t <= KSEL; ++t) {
        double mv = v[0]; int ms = 0;
        #pragma unroll
        for (int s = 1; s < 16; ++s) { if (v[s] < mv) { mv = v[s]; ms = s; } }
        int mid = ms * 64 + lane;
        #pragma unroll
        for (int off = 1; off < 64; off <<= 1) {
            double ov = __shfl_xor(mv, off);
            int oid  = __shfl_xor(mid, off);
            if (ov < mv || (ov == mv && oid < mid)) { mv = ov; mid = oid; }
        }
        kth = mv;
        if (t < KSEL) {
            #pragma unroll
            for (int s = 0; s < 16; ++s) {
                if (s * 64 + lane == mid) v[s] = 1e300;
            }
        }
    }
    if (lane == 0) sel[(size_t)b0 * NN + rowc] = sqrt(kth);
}

// ---------------- K5: R2[b] = (mean_n sel)^2
__global__ __launch_bounds__(256) void k_R(const double* __restrict__ sel,
                                           double* __restrict__ R2v, int b0) {
    int b = b0 + blockIdx.x;
    int tid = threadIdx.x;
    const double* s = sel + (size_t)b * NN;
    double acc = s[tid] + s[tid + 256] + s[tid + 512] + s[tid + 768];
    __shared__ double red[256];
    red[tid] = acc; __syncthreads();
    for (int st = 128; st > 0; st >>= 1) {
        if (tid < st) red[tid] += red[tid + st];
        __syncthreads();
    }
    if (tid == 0) { double R = red[0] / (double)NN; R2v[b] = R * R; }
}

// ---------------- K6: per-row counts (samples: d2<R2, neighbors: adj&&d2>0&&d2<R2)
__global__ __launch_bounds__(256) void k_counts(const double* __restrict__ d2buf,
                                                const float* __restrict__ adj,
                                                const double* __restrict__ R2v,
                                                int* __restrict__ samplesN,
                                                int* __restrict__ neighborN,
                                                int* __restrict__ ssum, int b0) {
    int rowc = blockIdx.x;
    int g = b0 * NN + rowc;
    int b = g >> 10;
    int n = g & (NN - 1);
    double R2 = R2v[b];
    const double* r = d2buf + (size_t)rowc * NN;
    const float* arow = adj + (size_t)n * NN;
    int tid = threadIdx.x;
    int cs = 0, cn = 0;
    for (int i = tid; i < NN; i += 256) {
        double d = r[i];
        int lt = (d < R2) ? 1 : 0;
        cs += lt;
        float a = arow[i];
        if (a != 0.0f && d > 0.0 && lt) cn++;
    }
    __shared__ int rs[256], rn[256];
    rs[tid] = cs; rn[tid] = cn; __syncthreads();
    for (int st = 128; st > 0; st >>= 1) {
        if (tid < st) { rs[tid] += rs[tid + st]; rn[tid] += rn[tid + st]; }
        __syncthreads();
    }
    if (tid == 0) {
        samplesN[g]  = rs[0];
        neighborN[g] = rn[0];
        atomicAdd(&ssum[b], rs[0]);
    }
}

// ---------------- K7: fp32 scores, exact reference op order
__global__ __launch_bounds__(256) void k_score(const int* __restrict__ samplesN,
                                               const int* __restrict__ neighborN,
                                               const int* __restrict__ ssum,
                                               const float* __restrict__ deg,
                                               float* __restrict__ scoreb,
                                               float* __restrict__ outScore) {
    int g = blockIdx.x * 256 + threadIdx.x;
    int b = g >> 10, n = g & (NN - 1);
    float s  = (float)samplesN[g];
    float nb = (float)neighborN[g];
    float means = (float)ssum[b] / 1024.0f;
    float spatial  = nb / deg[n];
    float temporal = s / (s + means);
    float sc = (2.0f - spatial) - temporal;
    scoreb[g] = sc;
    outScore[g] = sc;
}

// ---------------- K8: stable double-argsort rank + keep mask
__global__ __launch_bounds__(1024) void k_rank(const float* __restrict__ scoreb,
                                               const float* __restrict__ pptr,
                                               float* __restrict__ keepf) {
    int b = blockIdx.x;
    int i = threadIdx.x;
    __shared__ float s[NN];
    s[i] = scoreb[b * NN + i];
    __syncthreads();
    float si = s[i];
    int rank = 0;
    for (int j = 0; j < NN; ++j) {
        float sj = s[j];
        if (sj < si || (sj == si && j < i)) rank++;
    }
    float cut = (float)NN * pptr[0];
    keepf[b * NN + i] = ((float)rank < cut) ? 1.0f : 0.0f;
}

// ---------------- K9: out = data * keep (broadcast over C,H)
__global__ __launch_bounds__(256) void k_apply(const float* __restrict__ data,
                                               const float* __restrict__ keepf,
                                               float* __restrict__ out) {
    size_t g4 = (size_t)blockIdx.x * 256 + threadIdx.x;
    size_t flat = g4 << 2;
    int w = (int)(flat & (NN - 1));
    int b = (int)(flat / ((size_t)NF * NN));
    float4 v = reinterpret_cast<const float4*>(data)[g4];
    const float4* kb = reinterpret_cast<const float4*>(keepf + b * NN + w);
    float4 kv = kb[0];
    float4 o;
    o.x = v.x * kv.x; o.y = v.y * kv.y; o.z = v.z * kv.z; o.w = v.w * kv.w;
    reinterpret_cast<float4*>(out)[g4] = o;
}

extern "C" void kernel_launch(void* const* d_in, const int* in_sizes, int n_in,
                              void* d_out, int out_size, void* d_ws, size_t ws_size,
                              hipStream_t stream) {
    const float* data = (const float*)d_in[0];
    const float* adj  = (const float*)d_in[1];
    const float* pptr = (const float*)d_in[4];
    float* out = (float*)d_out;
    float* outScore = out + (size_t)NB * NF * NN;

    char* w = (char*)d_ws;
    size_t off = 0;
    auto alloc = [&](size_t bytes) -> void* {
        off = (off + 255) & ~(size_t)255;
        void* p = w + off;
        off += bytes;
        return p;
    };
    double* meanv  = (double*)alloc((size_t)NB * NF * 8);
    double* invv   = (double*)alloc((size_t)NB * NF * 8);
    double* sq     = (double*)alloc((size_t)NB * NN * 8);
    double* psum   = (double*)alloc((size_t)NB * 8 * NN * 8);
    double* sel    = (double*)alloc((size_t)NB * NN * 8);
    double* R2v    = (double*)alloc((size_t)NB * 8);
    int* samplesN  = (int*)alloc((size_t)NB * NN * 4);
    int* neighborN = (int*)alloc((size_t)NB * NN * 4);
    int* ssum      = (int*)alloc((size_t)NB * 4);
    float* deg     = (float*)alloc((size_t)NN * 4);
    float* scoreb  = (float*)alloc((size_t)NB * NN * 4);
    float* keepf   = (float*)alloc((size_t)NB * NN * 4);
    off = (off + 255) & ~(size_t)255;
    size_t rem = (ws_size > off) ? (ws_size - off) : 0;
    int chunk = (int)(rem / ((size_t)NN * NN * 8));
    if (chunk > NB) chunk = NB;
    if (chunk < 1) chunk = 1;
    double* d2buf = (double*)(w + off);

    hipMemsetAsync(ssum, 0, NB * 4, stream);
    k_stats<<<NB * NF, 256, 0, stream>>>(data, meanv, invv);
    k_sq1<<<dim3(NB * 4, 8), 256, 0, stream>>>(data, meanv, invv, psum);
    k_sq2<<<NB * NN / 256, 256, 0, stream>>>(psum, sq);
    k_deg<<<NN, 256, 0, stream>>>(adj, deg);

    for (int b0 = 0; b0 < NB; b0 += chunk) {
        int c = (NB - b0 < chunk) ? (NB - b0) : chunk;
        dim3 gg(36, 1, c);
        k_gemm_sym<<<gg, 512, 0, stream>>>(data, meanv, invv, sq, d2buf, b0);
        k_select<<<c * NN / 4, 256, 0, stream>>>(d2buf, sel, b0);
        k_R<<<c, 256, 0, stream>>>(sel, R2v, b0);
        k_counts<<<c * NN, 256, 0, stream>>>(d2buf, adj, R2v, samplesN, neighborN, ssum, b0);
    }

    k_score<<<NB * NN / 256, 256, 0, stream>>>(samplesN, neighborN, ssum, deg, scoreb, outScore);
    k_rank<<<NB, 1024, 0, stream>>>(scoreb, pptr, keepf);
    k_apply<<<(NB * NF * NN) / (256 * 4), 256, 0, stream>>>(data, keepf, out);
}

// Round 9
// 795.625 us; speedup vs baseline: 1.1431x; 1.1295x over previous
//
#include <hip/hip_runtime.h>
#include <math.h>

#define NB 16
#define NF 768
#define NN 1024
#define KSEL 30

// ---------------- K1: per-(b,f) mean and 1/(std+1e-6) over the 1024 contiguous samples
__global__ __launch_bounds__(256) void k_stats(const float* __restrict__ data,
                                               double* __restrict__ meanv,
                                               double* __restrict__ invv) {
    int bf = blockIdx.x;
    int tid = threadIdx.x;
    const float4* p = reinterpret_cast<const float4*>(data + (size_t)bf * NN);
    float4 v = p[tid];
    double s  = (double)v.x + (double)v.y + (double)v.z + (double)v.w;
    double s2 = (double)v.x * (double)v.x + (double)v.y * (double)v.y +
                (double)v.z * (double)v.z + (double)v.w * (double)v.w;
    __shared__ double r1[256], r2[256];
    r1[tid] = s; r2[tid] = s2;
    __syncthreads();
    for (int st = 128; st > 0; st >>= 1) {
        if (tid < st) { r1[tid] += r1[tid + st]; r2[tid] += r2[tid + st]; }
        __syncthreads();
    }
    if (tid == 0) {
        double S = r1[0], S2 = r2[0];
        double mean = S / (double)NN;
        double var = (S2 - S * mean) / (double)(NN - 1);
        if (var < 0.0) var = 0.0;
        meanv[bf] = mean;
        invv[bf]  = 1.0 / (sqrt(var) + 1e-6);
    }
}

// ---------------- K2a: partial sq over f-chunks of 96 (512 blocks for parallelism)
__global__ __launch_bounds__(256) void k_sq1(const float* __restrict__ data,
                                             const double* __restrict__ meanv,
                                             const double* __restrict__ invv,
                                             double* __restrict__ psum) {
    int b = blockIdx.x >> 2;
    int n = ((blockIdx.x & 3) << 8) + threadIdx.x;
    int y = blockIdx.y;                 // f-chunk 0..7
    const float* base = data + (size_t)b * NF * NN;
    const double* mb = meanv + (size_t)b * NF;
    const double* ib = invv + (size_t)b * NF;
    double acc = 0.0;
    int f0 = y * 96;
    for (int f = f0; f < f0 + 96; ++f) {
        float x = base[(size_t)f * NN + n];
        float xn = (float)(((double)x - mb[f]) * ib[f]);
        acc = fma((double)xn, (double)xn, acc);
    }
    psum[((size_t)(b * 8 + y)) * NN + n] = acc;
}

// ---------------- K2b: reduce 8 partials -> sq[b,n]
__global__ __launch_bounds__(256) void k_sq2(const double* __restrict__ psum,
                                             double* __restrict__ sq) {
    int g = blockIdx.x * 256 + threadIdx.x;   // 0..16383
    int b = g >> 10, n = g & (NN - 1);
    double acc = 0.0;
    #pragma unroll
    for (int y = 0; y < 8; ++y) acc += psum[((size_t)(b * 8 + y)) * NN + n];
    sq[g] = acc;
}

// ---------------- K0: deg[n] = row-sum of adj (coalesced, one block per row)
__global__ __launch_bounds__(256) void k_deg(const float* __restrict__ adj, float* __restrict__ deg) {
    int n = blockIdx.x;
    int tid = threadIdx.x;
    const float4* row = reinterpret_cast<const float4*>(adj + (size_t)n * NN);
    float4 v = row[tid];
    float s = v.x + v.y + v.z + v.w;
    __shared__ float red[256];
    red[tid] = s; __syncthreads();
    for (int st = 128; st > 0; st >>= 1) {
        if (tid < st) red[tid] += red[tid + st];
        __syncthreads();
    }
    if (tid == 0) deg[n] = red[0];
}

// ---------------- K3: symmetric batched Gram + d2 epilogue (f64 accum)
// Round-5 proven structure: 64x64 tiles, 4x4 acc, triangular pairs (136 of 256).
// __launch_bounds__(256,4): 4 waves/EU -> 128 arch-VGPR budget so acc[4][4]
// stays in arch VGPRs (round 5's VGPR_Count=32 implies AGPR churn around
// every v_fma_f64 - the suspected 5x VALU-issue inflation).
__global__ __launch_bounds__(256, 4) void k_gemm_sym(const float* __restrict__ data,
                                                     const double* __restrict__ meanv,
                                                     const double* __restrict__ invv,
                                                     const double* __restrict__ sq,
                                                     double* __restrict__ d2buf, int b0) {
    __shared__ float As[32][64];
    __shared__ float Bs[32][64];
    int tid = threadIdx.x;
    int tx = tid & 15, ty = tid >> 4;
    // triangular decode over 16x16 tiles of 64: t in [0,136), ti <= tj
    int t = blockIdx.x;
    int ti = 0, rem = t;
    while (rem >= 16 - ti) { rem -= 16 - ti; ++ti; }
    int tj = ti + rem;
    int n0 = ti * 64, m0 = tj * 64;
    int bb = blockIdx.z;
    int b = b0 + bb;
    const float* base = data + (size_t)b * NF * NN;
    const double* mb = meanv + (size_t)b * NF;
    const double* ib = invv + (size_t)b * NF;
    double acc[4][4] = {{0.0}};
    for (int f0 = 0; f0 < NF; f0 += 32) {
        #pragma unroll
        for (int r = 0; r < 2; ++r) {
            int idx = r * 256 + tid;
            int k = idx >> 4;
            int j4 = idx & 15;
            double mk = mb[f0 + k], ik = ib[f0 + k];
            const float4* pa = reinterpret_cast<const float4*>(base + (size_t)(f0 + k) * NN + n0);
            const float4* pb = reinterpret_cast<const float4*>(base + (size_t)(f0 + k) * NN + m0);
            float4 a = pa[j4], c = pb[j4];
            float4 an, cn;
            an.x = (float)(((double)a.x - mk) * ik);
            an.y = (float)(((double)a.y - mk) * ik);
            an.z = (float)(((double)a.z - mk) * ik);
            an.w = (float)(((double)a.w - mk) * ik);
            cn.x = (float)(((double)c.x - mk) * ik);
            cn.y = (float)(((double)c.y - mk) * ik);
            cn.z = (float)(((double)c.z - mk) * ik);
            cn.w = (float)(((double)c.w - mk) * ik);
            reinterpret_cast<float4*>(&As[k][0])[j4] = an;
            reinterpret_cast<float4*>(&Bs[k][0])[j4] = cn;
        }
        __syncthreads();
        #pragma unroll 8
        for (int k = 0; k < 32; ++k) {
            float4 av = reinterpret_cast<const float4*>(&As[k][0])[tx];
            float4 bv = reinterpret_cast<const float4*>(&Bs[k][0])[ty];
            double a0 = av.x, a1 = av.y, a2 = av.z, a3 = av.w;
            double b0d = bv.x, b1d = bv.y, b2d = bv.z, b3d = bv.w;
            acc[0][0] = fma(a0, b0d, acc[0][0]);
            acc[0][1] = fma(a0, b1d, acc[0][1]);
            acc[0][2] = fma(a0, b2d, acc[0][2]);
            acc[0][3] = fma(a0, b3d, acc[0][3]);
            acc[1][0] = fma(a1, b0d, acc[1][0]);
            acc[1][1] = fma(a1, b1d, acc[1][1]);
            acc[1][2] = fma(a1, b2d, acc[1][2]);
            acc[1][3] = fma(a1, b3d, acc[1][3]);
            acc[2][0] = fma(a2, b0d, acc[2][0]);
            acc[2][1] = fma(a2, b1d, acc[2][1]);
            acc[2][2] = fma(a2, b2d, acc[2][2]);
            acc[2][3] = fma(a2, b3d, acc[2][3]);
            acc[3][0] = fma(a3, b0d, acc[3][0]);
            acc[3][1] = fma(a3, b1d, acc[3][1]);
            acc[3][2] = fma(a3, b2d, acc[3][2]);
            acc[3][3] = fma(a3, b3d, acc[3][3]);
        }
        __syncthreads();
    }
    const double* sqb = sq + (size_t)b * NN;
    bool mirror = (ti != tj);
    #pragma unroll
    for (int i = 0; i < 4; ++i) {
        int n = n0 + tx * 4 + i;
        double sn = sqb[n];
        #pragma unroll
        for (int j = 0; j < 4; ++j) {
            int m = m0 + ty * 4 + j;
            double d2 = sn + sqb[m] - 2.0 * acc[i][j];
            if (d2 < 0.0) d2 = 0.0;
            d2buf[((size_t)bb * NN + n) * NN + m] = d2;
            if (mirror) d2buf[((size_t)bb * NN + m) * NN + n] = d2;
        }
    }
}

// ---------------- K4: per-row 31st smallest (index KSEL of ascending sort, diag included)
__global__ __launch_bounds__(256) void k_select(const double* __restrict__ d2buf,
                                                double* __restrict__ sel, int b0) {
    int rowc = blockIdx.x * 4 + (threadIdx.x >> 6);  // row within chunk
    int lane = threadIdx.x & 63;
    const double* r = d2buf + (size_t)rowc * NN;
    double v[16];
    #pragma unroll
    for (int s = 0; s < 16; ++s) v[s] = r[s * 64 + lane];
    double kth = 0.0;
    for (int t = 0; t <= KSEL; ++t) {
        double mv = v[0]; int ms = 0;
        #pragma unroll
        for (int s = 1; s < 16; ++s) { if (v[s] < mv) { mv = v[s]; ms = s; } }
        int mid = ms * 64 + lane;
        #pragma unroll
        for (int off = 1; off < 64; off <<= 1) {
            double ov = __shfl_xor(mv, off);
            int oid  = __shfl_xor(mid, off);
            if (ov < mv || (ov == mv && oid < mid)) { mv = ov; mid = oid; }
        }
        kth = mv;
        if (t < KSEL) {
            #pragma unroll
            for (int s = 0; s < 16; ++s) {
                if (s * 64 + lane == mid) v[s] = 1e300;
            }
        }
    }
    if (lane == 0) sel[(size_t)b0 * NN + rowc] = sqrt(kth);
}

// ---------------- K5: R2[b] = (mean_n sel)^2
__global__ __launch_bounds__(256) void k_R(const double* __restrict__ sel,
                                           double* __restrict__ R2v, int b0) {
    int b = b0 + blockIdx.x;
    int tid = threadIdx.x;
    const double* s = sel + (size_t)b * NN;
    double acc = s[tid] + s[tid + 256] + s[tid + 512] + s[tid + 768];
    __shared__ double red[256];
    red[tid] = acc; __syncthreads();
    for (int st = 128; st > 0; st >>= 1) {
        if (tid < st) red[tid] += red[tid + st];
        __syncthreads();
    }
    if (tid == 0) { double R = red[0] / (double)NN; R2v[b] = R * R; }
}

// ---------------- K6: per-row counts (samples: d2<R2, neighbors: adj&&d2>0&&d2<R2)
__global__ __launch_bounds__(256) void k_counts(const double* __restrict__ d2buf,
                                                const float* __restrict__ adj,
                                                const double* __restrict__ R2v,
                                                int* __restrict__ samplesN,
                                                int* __restrict__ neighborN,
                                                int* __restrict__ ssum, int b0) {
    int rowc = blockIdx.x;
    int g = b0 * NN + rowc;
    int b = g >> 10;
    int n = g & (NN - 1);
    double R2 = R2v[b];
    const double* r = d2buf + (size_t)rowc * NN;
    const float* arow = adj + (size_t)n * NN;
    int tid = threadIdx.x;
    int cs = 0, cn = 0;
    for (int i = tid; i < NN; i += 256) {
        double d = r[i];
        int lt = (d < R2) ? 1 : 0;
        cs += lt;
        float a = arow[i];
        if (a != 0.0f && d > 0.0 && lt) cn++;
    }
    __shared__ int rs[256], rn[256];
    rs[tid] = cs; rn[tid] = cn; __syncthreads();
    for (int st = 128; st > 0; st >>= 1) {
        if (tid < st) { rs[tid] += rs[tid + st]; rn[tid] += rn[tid + st]; }
        __syncthreads();
    }
    if (tid == 0) {
        samplesN[g]  = rs[0];
        neighborN[g] = rn[0];
        atomicAdd(&ssum[b], rs[0]);
    }
}

// ---------------- K7: fp32 scores, exact reference op order
__global__ __launch_bounds__(256) void k_score(const int* __restrict__ samplesN,
                                               const int* __restrict__ neighborN,
                                               const int* __restrict__ ssum,
                                               const float* __restrict__ deg,
                                               float* __restrict__ scoreb,
                                               float* __restrict__ outScore) {
    int g = blockIdx.x * 256 + threadIdx.x;
    int b = g >> 10, n = g & (NN - 1);
    float s  = (float)samplesN[g];
    float nb = (float)neighborN[g];
    float means = (float)ssum[b] / 1024.0f;
    float spatial  = nb / deg[n];
    float temporal = s / (s + means);
    float sc = (2.0f - spatial) - temporal;
    scoreb[g] = sc;
    outScore[g] = sc;
}

// ---------------- K8: stable double-argsort rank + keep mask
__global__ __launch_bounds__(1024) void k_rank(const float* __restrict__ scoreb,
                                               const float* __restrict__ pptr,
                                               float* __restrict__ keepf) {
    int b = blockIdx.x;
    int i = threadIdx.x;
    __shared__ float s[NN];
    s[i] = scoreb[b * NN + i];
    __syncthreads();
    float si = s[i];
    int rank = 0;
    for (int j = 0; j < NN; ++j) {
        float sj = s[j];
        if (sj < si || (sj == si && j < i)) rank++;
    }
    float cut = (float)NN * pptr[0];
    keepf[b * NN + i] = ((float)rank < cut) ? 1.0f : 0.0f;
}

// ---------------- K9: out = data * keep (broadcast over C,H)
__global__ __launch_bounds__(256) void k_apply(const float* __restrict__ data,
                                               const float* __restrict__ keepf,
                                               float* __restrict__ out) {
    size_t g4 = (size_t)blockIdx.x * 256 + threadIdx.x;
    size_t flat = g4 << 2;
    int w = (int)(flat & (NN - 1));
    int b = (int)(flat / ((size_t)NF * NN));
    float4 v = reinterpret_cast<const float4*>(data)[g4];
    const float4* kb = reinterpret_cast<const float4*>(keepf + b * NN + w);
    float4 kv = kb[0];
    float4 o;
    o.x = v.x * kv.x; o.y = v.y * kv.y; o.z = v.z * kv.z; o.w = v.w * kv.w;
    reinterpret_cast<float4*>(out)[g4] = o;
}

extern "C" void kernel_launch(void* const* d_in, const int* in_sizes, int n_in,
                              void* d_out, int out_size, void* d_ws, size_t ws_size,
                              hipStream_t stream) {
    const float* data = (const float*)d_in[0];
    const float* adj  = (const float*)d_in[1];
    const float* pptr = (const float*)d_in[4];
    float* out = (float*)d_out;
    float* outScore = out + (size_t)NB * NF * NN;

    char* w = (char*)d_ws;
    size_t off = 0;
    auto alloc = [&](size_t bytes) -> void* {
        off = (off + 255) & ~(size_t)255;
        void* p = w + off;
        off += bytes;
        return p;
    };
    double* meanv  = (double*)alloc((size_t)NB * NF * 8);
    double* invv   = (double*)alloc((size_t)NB * NF * 8);
    double* sq     = (double*)alloc((size_t)NB * NN * 8);
    double* psum   = (double*)alloc((size_t)NB * 8 * NN * 8);
    double* sel    = (double*)alloc((size_t)NB * NN * 8);
    double* R2v    = (double*)alloc((size_t)NB * 8);
    int* samplesN  = (int*)alloc((size_t)NB * NN * 4);
    int* neighborN = (int*)alloc((size_t)NB * NN * 4);
    int* ssum      = (int*)alloc((size_t)NB * 4);
    float* deg     = (float*)alloc((size_t)NN * 4);
    float* scoreb  = (float*)alloc((size_t)NB * NN * 4);
    float* keepf   = (float*)alloc((size_t)NB * NN * 4);
    off = (off + 255) & ~(size_t)255;
    size_t rem = (ws_size > off) ? (ws_size - off) : 0;
    int chunk = (int)(rem / ((size_t)NN * NN * 8));
    if (chunk > NB) chunk = NB;
    if (chunk < 1) chunk = 1;
    double* d2buf = (double*)(w + off);

    hipMemsetAsync(ssum, 0, NB * 4, stream);
    k_stats<<<NB * NF, 256, 0, stream>>>(data, meanv, invv);
    k_sq1<<<dim3(NB * 4, 8), 256, 0, stream>>>(data, meanv, invv, psum);
    k_sq2<<<NB * NN / 256, 256, 0, stream>>>(psum, sq);
    k_deg<<<NN, 256, 0, stream>>>(adj, deg);

    for (int b0 = 0; b0 < NB; b0 += chunk) {
        int c = (NB - b0 < chunk) ? (NB - b0) : chunk;
        dim3 gg(136, 1, c);
        k_gemm_sym<<<gg, 256, 0, stream>>>(data, meanv, invv, sq, d2buf, b0);
        k_select<<<c * NN / 4, 256, 0, stream>>>(d2buf, sel, b0);
        k_R<<<c, 256, 0, stream>>>(sel, R2v, b0);
        k_counts<<<c * NN, 256, 0, stream>>>(d2buf, adj, R2v, samplesN, neighborN, ssum, b0);
    }

    k_score<<<NB * NN / 256, 256, 0, stream>>>(samplesN, neighborN, ssum, deg, scoreb, outScore);
    k_rank<<<NB, 1024, 0, stream>>>(scoreb, pptr, keepf);
    k_apply<<<(NB * NF * NN) / (256 * 4), 256, 0, stream>>>(data, keepf, out);
}